// Round 13
// baseline (319.243 us; speedup 1.0000x reference)
//
#include <hip/hip_runtime.h>
#include <hip/hip_fp16.h>
#include <math.h>

#define B_   2
#define C_   8
#define NB_  3
#define X_   80
#define Y_   80
#define M_   4096
#define P_   6400
#define NJ   24
#define KS   3          // k-steps of 32 (y padded 80->96)
#define NF   2          // n-frags (j padded 24->32)
#define TWO_PI 6.2831853071795864769f

typedef _Float16 f16x8 __attribute__((ext_vector_type(8)));
typedef float    f32x4 __attribute__((ext_vector_type(4)));
typedef unsigned int u32x4 __attribute__((ext_vector_type(4)));

#define T1_ (B_*X_*KS*NF*64*8)   // 491,520
#define T2_ (B_*256*KS*512)      // 786,432

__device__ __forceinline__ int klocal(int lane, int i) {
  return ((lane >> 4) << 2) + (i & 3) + ((i >> 2) << 4);
}

// exact-reduced sincos of (-2*pi*t_rev): t in revolutions, |t| up to ~20.
// t - rintf(t) is exact in fp32; __sincosf then sees |arg| <= pi.
__device__ __forceinline__ void sincos_rev(float t, float* s, float* c) {
  t -= rintf(t);
  __sincosf(-TWO_PI * t, s, c);
}

// ---------- kernel 1 (fused prep): r12-verbatim (verified passing).
// Bf layout (f16): (b*80+x)*6144 + (ks*2+nf)*1024 + {0:re,512:im} + lane*8 + i
//   j-mapping: j = nb*8 + c
// A layout  (f16): ((b*256+m16)*3+ks)*512 + lane*8 + i   (includes 1/80 norm)
__global__ void prep_fused(const float* __restrict__ xin, const float* __restrict__ maps,
                           const float* __restrict__ coord,
                           _Float16* __restrict__ Bf,
                           _Float16* __restrict__ ARe, _Float16* __restrict__ AIm) {
  int t = blockIdx.x * blockDim.x + threadIdx.x;
  if (t < T1_) {
    int i    = t & 7;
    int lane = (t >> 3) & 63;
    int nf   = (t >> 9) & 1;
    int rest = t >> 10;
    int ks   = rest % 3; rest /= 3;
    int x    = rest % 80;
    int b    = rest / 80;

    int j = nf*16 + (lane & 15);
    int y = ks*32 + klocal(lane, i);
    float re = 0.f, im = 0.f;
    if (y < Y_ && j < NJ) {
      int c = j & 7, nb = j >> 3;
      int p = x*Y_ + y;
      const float* xp = xin  + (((size_t)b*NB_ + nb)*P_ + p)*2;
      const float* mp = maps + ((((size_t)b*C_ + c)*NB_ + nb)*P_ + p)*2;
      float xr = xp[0], xi2 = xp[1], mr = mp[0], mi = mp[1];
      re = mr*xr - mi*xi2;
      im = mr*xi2 + mi*xr;
    }
    size_t base = (size_t)((b*X_ + x)*6 + (ks*2 + nf)) * 1024;
    Bf[base + lane*8 + i]       = (_Float16)re;
    Bf[base + 512 + lane*8 + i] = (_Float16)im;
  } else {
    int u = t - T1_;
    int i    = u & 7;
    int lane = (u >> 3) & 63;
    int q    = u >> 9;           // (b*256 + m16)*3 + ks
    int ks   = q % 3;
    int bm   = q / 3;
    int m16  = bm & 255;
    int b    = bm >> 8;

    int m = m16*16 + (lane & 15);
    int y = ks*32 + klocal(lane, i);
    float re = 0.f, im = 0.f;
    if (y < Y_) {
      float c1 = coord[((size_t)b*M_ + m)*2 + 1];
      float s, c;
      sincos_rev(c1 * (float)(y - 40) * (1.0f/80.0f), &s, &c);
      re = c * (1.0f/80.0f);
      im = s * (1.0f/80.0f);
    }
    ARe[u] = (_Float16)re;
    AIm[u] = (_Float16)im;
  }
}

// Stage one x-row's B tile (12,288 B, contiguous) global->LDS (r10-verbatim).
__device__ __forceinline__ void stage_b(const _Float16* src, _Float16* dst, int tid) {
  int wave = tid >> 6, lane = tid & 63;
  #pragma unroll
  for (int u = 0; u < 3; u++) {
    int off = wave*3072 + u*1024;    // bytes
    __builtin_amdgcn_global_load_lds(
      (const __attribute__((address_space(1))) void*)((const char*)src + off + lane*16),
      (__attribute__((address_space(3))) void*)((char*)dst + off),
      16, 0, 0);
  }
}

// ---------- kernel 2: r12 main (Gauss 3-MFMA), ONE delta: occupancy.
// Templated on XPB (x-rows per block); grid.y = X_/XPB; launch_bounds(256,4)
// so 4 blocks/CU co-reside (VGPR ~100 <= 128, LDS 26.5KB x 4 <= 160KB).
template <int XPB>
__global__ __launch_bounds__(256, 4) void main_mfma(
    const float* __restrict__ coord, const _Float16* __restrict__ Bf,
    const _Float16* __restrict__ ARe, const _Float16* __restrict__ AIm,
    const float* __restrict__ phi, float* __restrict__ partial) {
  __shared__ unsigned int extab[XPB * 128];    // packed half2(cos,sin)
  __shared__ _Float16 bsm[2][6144];            // double-buffered B tile, 24 KB

  int mb   = blockIdx.x;          // 32 m-tiles of 128
  int xs   = blockIdx.y;          // x-split
  int b    = blockIdx.z;
  int tid  = threadIdx.x;
  int wave = tid >> 6, lane = tid & 63;
  int mblock = mb * 128;

  const _Float16* bfbase = Bf + (size_t)(b*X_ + xs*XPB) * 6144;

  // prologue: stage xi=0 (drained by the first __syncthreads below)
  stage_b(bfbase, bsm[0], tid);

  // ex table for THIS block's x-slice only: exp(-2*pi*i * coord0 * (x-40)/80)
  for (int t = tid; t < XPB*128; t += 256) {
    int xloc = t >> 7, ml = t & 127;
    int x = xs*XPB + xloc;
    float c0 = coord[((size_t)b*M_ + mblock + ml)*2 + 0];
    float s, c;
    sincos_rev(c0 * (float)(x - 40) * (1.0f/80.0f), &s, &c);
    __half2 h = __floats2half2_rn(c, s);
    extab[t] = *(unsigned int*)&h;
  }

  // ey A-fragments: load precomputed (L2-resident); as_ = ar+ai for Gauss M3
  int mtile = mblock + wave*32;
  f16x8 ar[2][KS], ai[2][KS], as_[2][KS];
  #pragma unroll
  for (int mf = 0; mf < 2; mf++) {
    int m16 = (mtile >> 4) + mf;
    #pragma unroll
    for (int ks = 0; ks < KS; ks++) {
      size_t o = (((size_t)(b*256 + m16)*3 + ks)*512) + lane*8;
      ar[mf][ks] = *(const f16x8*)(ARe + o);
      ai[mf][ks] = *(const f16x8*)(AIm + o);
      as_[mf][ks] = ar[mf][ks] + ai[mf][ks];
    }
  }
  __syncthreads();   // extab ready + stage(xi=0) drained (vmcnt 0 at barrier)

  f32x4 outr[2][NF], outi[2][NF];
  #pragma unroll
  for (int mf = 0; mf < 2; mf++)
    #pragma unroll
    for (int nf = 0; nf < NF; nf++) {
      outr[mf][nf] = (f32x4){0.f,0.f,0.f,0.f};
      outi[mf][nf] = (f32x4){0.f,0.f,0.f,0.f};
    }

  int cur = 0;
  #pragma unroll
  for (int xi = 0; xi < XPB; xi++) {
    if (xi + 1 < XPB)
      stage_b(bfbase + (size_t)(xi + 1) * 6144, bsm[cur ^ 1], tid);

    const _Float16* fb = bsm[cur];
    f16x8 br[KS][NF], bi[KS][NF], bs[KS][NF];
    #pragma unroll
    for (int ks = 0; ks < KS; ks++)
      #pragma unroll
      for (int nf = 0; nf < NF; nf++) {
        const _Float16* p = fb + (ks*2 + nf)*1024 + lane*8;
        br[ks][nf] = *(const f16x8*)p;
        bi[ks][nf] = *(const f16x8*)(p + 512);
        bs[ks][nf] = br[ks][nf] + bi[ks][nf];
      }

    f32x4 M1[2][NF], M2[2][NF], M3[2][NF];
    #pragma unroll
    for (int mf = 0; mf < 2; mf++)
      #pragma unroll
      for (int nf = 0; nf < NF; nf++) {
        M1[mf][nf] = (f32x4){0.f,0.f,0.f,0.f};
        M2[mf][nf] = (f32x4){0.f,0.f,0.f,0.f};
        M3[mf][nf] = (f32x4){0.f,0.f,0.f,0.f};
      }

    #pragma unroll
    for (int ks = 0; ks < KS; ks++)
      #pragma unroll
      for (int mf = 0; mf < 2; mf++)
        #pragma unroll
        for (int nf = 0; nf < NF; nf++) {
          M1[mf][nf] = __builtin_amdgcn_mfma_f32_16x16x32_f16(ar[mf][ks],  br[ks][nf], M1[mf][nf], 0, 0, 0);
          M2[mf][nf] = __builtin_amdgcn_mfma_f32_16x16x32_f16(ai[mf][ks],  bi[ks][nf], M2[mf][nf], 0, 0, 0);
          M3[mf][nf] = __builtin_amdgcn_mfma_f32_16x16x32_f16(as_[mf][ks], bs[ks][nf], M3[mf][nf], 0, 0, 0);
        }

    // epilogue: Tr = M1-M2, Ti = M3-M1-M2; out += ex(m,x) * T
    #pragma unroll
    for (int mf = 0; mf < 2; mf++) {
      #pragma unroll
      for (int nf = 0; nf < NF; nf++) {
        f32x4 tr = M1[mf][nf] - M2[mf][nf];
        f32x4 ti = M3[mf][nf] - M1[mf][nf] - M2[mf][nf];
        #pragma unroll
        for (int r = 0; r < 4; r++) {
          int ml = wave*32 + mf*16 + ((lane >> 4) << 2) + r;
          unsigned int u = extab[xi*128 + ml];
          __half2 h = *(__half2*)&u;
          float exr = __low2float(h), exi = __high2float(h);
          outr[mf][nf][r] += exr*tr[r] - exi*ti[r];
          outi[mf][nf][r] += exr*ti[r] + exi*tr[r];
        }
      }
    }

    __syncthreads();   // all waves done reading bsm[cur]; stage(xi+1) drained
    cur ^= 1;
  }

  // ---- in-register phi + band reduction (r12 verbatim) ----
  int j0 = lane & 15;
  int row = (lane >> 4) << 2;
  const float* phb = phi + (size_t)b*NB_*M_*2;
  #pragma unroll
  for (int mf = 0; mf < 2; mf++)
    #pragma unroll
    for (int r = 0; r < 4; r++) {
      int m = mtile + mf*16 + row + r;
      const float* p0 = phb + ((size_t)(j0 >> 3)*M_ + m)*2;
      float p0r = p0[0], p0i = p0[1];
      float a0r = outr[mf][0][r], a0i = outi[mf][0][r];
      float vr = p0r*a0r - p0i*a0i;
      float vi = p0r*a0i + p0i*a0r;
      vr += __shfl_xor(vr, 8);
      vi += __shfl_xor(vi, 8);
      const float* p1 = phb + ((size_t)2*M_ + m)*2;
      float p1r = p1[0], p1i = p1[1];
      float a1r = outr[mf][1][r], a1i = outi[mf][1][r];
      vr += p1r*a1r - p1i*a1i;
      vi += p1r*a1i + p1i*a1r;
      if (j0 < 8) {
        int c = j0;
        size_t o = (((size_t)xs*B_ + b)*C_ + c)*M_ + m;
        ((float2*)partial)[o] = make_float2(vr, vi);
      }
    }
}

// ---------- kernel 3: combine (runtime XS)
__global__ void combine3(const float* __restrict__ partial, float* __restrict__ out, int XS) {
  int t = blockIdx.x * blockDim.x + threadIdx.x;   // (b, c, m), m fastest
  if (t >= B_*C_*M_) return;
  int m = t & (M_ - 1);
  int c = (t >> 12) & 7;
  int b = t >> 15;
  float sr = 0.f, si = 0.f;
  for (int xs = 0; xs < XS; xs++) {
    const float2 v = ((const float2*)partial)[(((size_t)xs*B_ + b)*C_ + c)*M_ + m];
    sr += v.x; si += v.y;
  }
  ((float2*)out)[((size_t)b*C_ + c)*M_ + m] = make_float2(sr, si);
}

extern "C" void kernel_launch(void* const* d_in, const int* in_sizes, int n_in,
                              void* d_out, int out_size, void* d_ws, size_t ws_size,
                              hipStream_t stream) {
  const float* xin   = (const float*)d_in[0];
  const float* maps  = (const float*)d_in[1];
  const float* phi   = (const float*)d_in[2];
  const float* coord = (const float*)d_in[3];
  float* out = (float*)d_out;

  const size_t bf_elems = (size_t)B_ * X_ * 6144;        // 983,040 f16
  const size_t af_elems = (size_t)B_ * 256 * KS * 512;   // 786,432 f16
  _Float16* Bf  = (_Float16*)d_ws;
  _Float16* ARe = Bf + bf_elems;
  _Float16* AIm = ARe + af_elems;
  float* partial = (float*)(AIm + af_elems);

  const size_t base_bytes = (bf_elems + 2*af_elems) * sizeof(_Float16);
  const size_t per_xs     = (size_t)B_*C_*M_*2*sizeof(float);   // 524,288 B
  int XS = (ws_size >= base_bytes + 16*per_xs) ? 16 : 8;

  {
    int total = T1_ + T2_;          // 1,277,952 -> 4992 blocks exactly
    prep_fused<<<(total + 255)/256, 256, 0, stream>>>(xin, maps, coord, Bf, ARe, AIm);
  }
  if (XS == 16) {
    dim3 g(M_/128, 16, B_);         // 1024 blocks = 4/CU
    main_mfma<5><<<g, 256, 0, stream>>>(coord, Bf, ARe, AIm, phi, partial);
  } else {
    dim3 g(M_/128, 8, B_);          // 512 blocks = 2/CU
    main_mfma<10><<<g, 256, 0, stream>>>(coord, Bf, ARe, AIm, phi, partial);
  }
  {
    int total = B_*C_*M_;           // 65,536
    combine3<<<(total + 255)/256, 256, 0, stream>>>(partial, out, XS);
  }
}

// Round 14
// 41.663 us; speedup vs baseline: 7.6624x; 7.6624x over previous
//
#include <hip/hip_runtime.h>
#include <hip/hip_fp16.h>
#include <math.h>

#define B_   2
#define C_   8
#define NB_  3
#define X_   80
#define Y_   80
#define M_   4096
#define P_   6400
#define NJ   24
#define KS   3          // k-steps of 32 (y padded 80->96)
#define NF   2          // n-frags (j padded 24->32)
#define TWO_PI 6.2831853071795864769f

typedef _Float16 f16x8 __attribute__((ext_vector_type(8)));
typedef float    f32x4 __attribute__((ext_vector_type(4)));
typedef unsigned int u32x4 __attribute__((ext_vector_type(4)));

#define T1_ (B_*X_*KS*NF*64*8)   // 491,520
#define T2_ (B_*256*KS*512)      // 786,432

__device__ __forceinline__ int klocal(int lane, int i) {
  return ((lane >> 4) << 2) + (i & 3) + ((i >> 2) << 4);
}

// exact-reduced sincos of (-2*pi*t_rev): t in revolutions, |t| up to ~20.
// t - rintf(t) is exact in fp32; __sincosf then sees |arg| <= pi.
__device__ __forceinline__ void sincos_rev(float t, float* s, float* c) {
  t -= rintf(t);
  __sincosf(-TWO_PI * t, s, c);
}

// ---------- kernel 1 (fused prep): r12-verbatim (verified passing).
// Bf layout (f16): (b*80+x)*6144 + (ks*2+nf)*1024 + {0:re,512:im} + lane*8 + i
//   j-mapping: j = nb*8 + c
// A layout  (f16): ((b*256+m16)*3+ks)*512 + lane*8 + i   (includes 1/80 norm)
__global__ void prep_fused(const float* __restrict__ xin, const float* __restrict__ maps,
                           const float* __restrict__ coord,
                           _Float16* __restrict__ Bf,
                           _Float16* __restrict__ ARe, _Float16* __restrict__ AIm) {
  int t = blockIdx.x * blockDim.x + threadIdx.x;
  if (t < T1_) {
    int i    = t & 7;
    int lane = (t >> 3) & 63;
    int nf   = (t >> 9) & 1;
    int rest = t >> 10;
    int ks   = rest % 3; rest /= 3;
    int x    = rest % 80;
    int b    = rest / 80;

    int j = nf*16 + (lane & 15);
    int y = ks*32 + klocal(lane, i);
    float re = 0.f, im = 0.f;
    if (y < Y_ && j < NJ) {
      int c = j & 7, nb = j >> 3;
      int p = x*Y_ + y;
      const float* xp = xin  + (((size_t)b*NB_ + nb)*P_ + p)*2;
      const float* mp = maps + ((((size_t)b*C_ + c)*NB_ + nb)*P_ + p)*2;
      float xr = xp[0], xi2 = xp[1], mr = mp[0], mi = mp[1];
      re = mr*xr - mi*xi2;
      im = mr*xi2 + mi*xr;
    }
    size_t base = (size_t)((b*X_ + x)*6 + (ks*2 + nf)) * 1024;
    Bf[base + lane*8 + i]       = (_Float16)re;
    Bf[base + 512 + lane*8 + i] = (_Float16)im;
  } else {
    int u = t - T1_;
    int i    = u & 7;
    int lane = (u >> 3) & 63;
    int q    = u >> 9;           // (b*256 + m16)*3 + ks
    int ks   = q % 3;
    int bm   = q / 3;
    int m16  = bm & 255;
    int b    = bm >> 8;

    int m = m16*16 + (lane & 15);
    int y = ks*32 + klocal(lane, i);
    float re = 0.f, im = 0.f;
    if (y < Y_) {
      float c1 = coord[((size_t)b*M_ + m)*2 + 1];
      float s, c;
      sincos_rev(c1 * (float)(y - 40) * (1.0f/80.0f), &s, &c);
      re = c * (1.0f/80.0f);
      im = s * (1.0f/80.0f);
    }
    ARe[u] = (_Float16)re;
    AIm[u] = (_Float16)im;
  }
}

// Stage one x-row's B tile (12,288 B, contiguous) global->LDS (r10-verbatim).
__device__ __forceinline__ void stage_b(const _Float16* src, _Float16* dst, int tid) {
  int wave = tid >> 6, lane = tid & 63;
  #pragma unroll
  for (int u = 0; u < 3; u++) {
    int off = wave*3072 + u*1024;    // bytes
    __builtin_amdgcn_global_load_lds(
      (const __attribute__((address_space(1))) void*)((const char*)src + off + lane*16),
      (__attribute__((address_space(3))) void*)((char*)dst + off),
      16, 0, 0);
  }
}

// ---------- kernel 2: r12 main (Gauss 3-MFMA), launch_bounds(256,2) UNCHANGED
// (r13 lesson: bounds(256,4) forced VGPR 64 -> 551MB scratch spills).
// Occupancy comes from the GRID: XS=16 -> 1024 blocks = 4 blocks/CU, legal
// because r12's allocation (VGPR=100 <= 128, LDS 27KB*4 <= 160KB) already
// permits 4 waves/SIMD. #pragma unroll 1 keeps the xi-loop rolled (r13's
// full unroll was the other pressure source).
template <int XPB>
__global__ __launch_bounds__(256, 2) void main_mfma(
    const float* __restrict__ coord, const _Float16* __restrict__ Bf,
    const _Float16* __restrict__ ARe, const _Float16* __restrict__ AIm,
    const float* __restrict__ phi, float* __restrict__ partial) {
  __shared__ unsigned int extab[XPB * 128];    // packed half2(cos,sin)
  __shared__ _Float16 bsm[2][6144];            // double-buffered B tile, 24 KB

  int mb   = blockIdx.x;          // 32 m-tiles of 128
  int xs   = blockIdx.y;          // x-split
  int b    = blockIdx.z;
  int tid  = threadIdx.x;
  int wave = tid >> 6, lane = tid & 63;
  int mblock = mb * 128;

  const _Float16* bfbase = Bf + (size_t)(b*X_ + xs*XPB) * 6144;

  // prologue: stage xi=0 (drained by the first __syncthreads below)
  stage_b(bfbase, bsm[0], tid);

  // ex table for THIS block's x-slice only: exp(-2*pi*i * coord0 * (x-40)/80)
  for (int t = tid; t < XPB*128; t += 256) {
    int xloc = t >> 7, ml = t & 127;
    int x = xs*XPB + xloc;
    float c0 = coord[((size_t)b*M_ + mblock + ml)*2 + 0];
    float s, c;
    sincos_rev(c0 * (float)(x - 40) * (1.0f/80.0f), &s, &c);
    __half2 h = __floats2half2_rn(c, s);
    extab[t] = *(unsigned int*)&h;
  }

  // ey A-fragments: load precomputed (L2-resident); as_ = ar+ai for Gauss M3
  int mtile = mblock + wave*32;
  f16x8 ar[2][KS], ai[2][KS], as_[2][KS];
  #pragma unroll
  for (int mf = 0; mf < 2; mf++) {
    int m16 = (mtile >> 4) + mf;
    #pragma unroll
    for (int ks = 0; ks < KS; ks++) {
      size_t o = (((size_t)(b*256 + m16)*3 + ks)*512) + lane*8;
      ar[mf][ks] = *(const f16x8*)(ARe + o);
      ai[mf][ks] = *(const f16x8*)(AIm + o);
      as_[mf][ks] = ar[mf][ks] + ai[mf][ks];
    }
  }
  __syncthreads();   // extab ready + stage(xi=0) drained (vmcnt 0 at barrier)

  f32x4 outr[2][NF], outi[2][NF];
  #pragma unroll
  for (int mf = 0; mf < 2; mf++)
    #pragma unroll
    for (int nf = 0; nf < NF; nf++) {
      outr[mf][nf] = (f32x4){0.f,0.f,0.f,0.f};
      outi[mf][nf] = (f32x4){0.f,0.f,0.f,0.f};
    }

  int cur = 0;
  #pragma unroll 1
  for (int xi = 0; xi < XPB; xi++) {
    if (xi + 1 < XPB)
      stage_b(bfbase + (size_t)(xi + 1) * 6144, bsm[cur ^ 1], tid);

    const _Float16* fb = bsm[cur];
    f16x8 br[KS][NF], bi[KS][NF], bs[KS][NF];
    #pragma unroll
    for (int ks = 0; ks < KS; ks++)
      #pragma unroll
      for (int nf = 0; nf < NF; nf++) {
        const _Float16* p = fb + (ks*2 + nf)*1024 + lane*8;
        br[ks][nf] = *(const f16x8*)p;
        bi[ks][nf] = *(const f16x8*)(p + 512);
        bs[ks][nf] = br[ks][nf] + bi[ks][nf];
      }

    f32x4 M1[2][NF], M2[2][NF], M3[2][NF];
    #pragma unroll
    for (int mf = 0; mf < 2; mf++)
      #pragma unroll
      for (int nf = 0; nf < NF; nf++) {
        M1[mf][nf] = (f32x4){0.f,0.f,0.f,0.f};
        M2[mf][nf] = (f32x4){0.f,0.f,0.f,0.f};
        M3[mf][nf] = (f32x4){0.f,0.f,0.f,0.f};
      }

    #pragma unroll
    for (int ks = 0; ks < KS; ks++)
      #pragma unroll
      for (int mf = 0; mf < 2; mf++)
        #pragma unroll
        for (int nf = 0; nf < NF; nf++) {
          M1[mf][nf] = __builtin_amdgcn_mfma_f32_16x16x32_f16(ar[mf][ks],  br[ks][nf], M1[mf][nf], 0, 0, 0);
          M2[mf][nf] = __builtin_amdgcn_mfma_f32_16x16x32_f16(ai[mf][ks],  bi[ks][nf], M2[mf][nf], 0, 0, 0);
          M3[mf][nf] = __builtin_amdgcn_mfma_f32_16x16x32_f16(as_[mf][ks], bs[ks][nf], M3[mf][nf], 0, 0, 0);
        }

    // epilogue: Tr = M1-M2, Ti = M3-M1-M2; out += ex(m,x) * T
    #pragma unroll
    for (int mf = 0; mf < 2; mf++) {
      #pragma unroll
      for (int nf = 0; nf < NF; nf++) {
        f32x4 tr = M1[mf][nf] - M2[mf][nf];
        f32x4 ti = M3[mf][nf] - M1[mf][nf] - M2[mf][nf];
        #pragma unroll
        for (int r = 0; r < 4; r++) {
          int ml = wave*32 + mf*16 + ((lane >> 4) << 2) + r;
          unsigned int u = extab[xi*128 + ml];
          __half2 h = *(__half2*)&u;
          float exr = __low2float(h), exi = __high2float(h);
          outr[mf][nf][r] += exr*tr[r] - exi*ti[r];
          outi[mf][nf][r] += exr*ti[r] + exi*tr[r];
        }
      }
    }

    __syncthreads();   // all waves done reading bsm[cur]; stage(xi+1) drained
    cur ^= 1;
  }

  // ---- in-register phi + band reduction (r12 verbatim) ----
  int j0 = lane & 15;
  int row = (lane >> 4) << 2;
  const float* phb = phi + (size_t)b*NB_*M_*2;
  #pragma unroll
  for (int mf = 0; mf < 2; mf++)
    #pragma unroll
    for (int r = 0; r < 4; r++) {
      int m = mtile + mf*16 + row + r;
      const float* p0 = phb + ((size_t)(j0 >> 3)*M_ + m)*2;
      float p0r = p0[0], p0i = p0[1];
      float a0r = outr[mf][0][r], a0i = outi[mf][0][r];
      float vr = p0r*a0r - p0i*a0i;
      float vi = p0r*a0i + p0i*a0r;
      vr += __shfl_xor(vr, 8);
      vi += __shfl_xor(vi, 8);
      const float* p1 = phb + ((size_t)2*M_ + m)*2;
      float p1r = p1[0], p1i = p1[1];
      float a1r = outr[mf][1][r], a1i = outi[mf][1][r];
      vr += p1r*a1r - p1i*a1i;
      vi += p1r*a1i + p1i*a1r;
      if (j0 < 8) {
        int c = j0;
        size_t o = (((size_t)xs*B_ + b)*C_ + c)*M_ + m;
        ((float2*)partial)[o] = make_float2(vr, vi);
      }
    }
}

// ---------- kernel 3: combine (runtime XS)
__global__ void combine3(const float* __restrict__ partial, float* __restrict__ out, int XS) {
  int t = blockIdx.x * blockDim.x + threadIdx.x;   // (b, c, m), m fastest
  if (t >= B_*C_*M_) return;
  int m = t & (M_ - 1);
  int c = (t >> 12) & 7;
  int b = t >> 15;
  float sr = 0.f, si = 0.f;
  for (int xs = 0; xs < XS; xs++) {
    const float2 v = ((const float2*)partial)[(((size_t)xs*B_ + b)*C_ + c)*M_ + m];
    sr += v.x; si += v.y;
  }
  ((float2*)out)[((size_t)b*C_ + c)*M_ + m] = make_float2(sr, si);
}

extern "C" void kernel_launch(void* const* d_in, const int* in_sizes, int n_in,
                              void* d_out, int out_size, void* d_ws, size_t ws_size,
                              hipStream_t stream) {
  const float* xin   = (const float*)d_in[0];
  const float* maps  = (const float*)d_in[1];
  const float* phi   = (const float*)d_in[2];
  const float* coord = (const float*)d_in[3];
  float* out = (float*)d_out;

  const size_t bf_elems = (size_t)B_ * X_ * 6144;        // 983,040 f16
  const size_t af_elems = (size_t)B_ * 256 * KS * 512;   // 786,432 f16
  _Float16* Bf  = (_Float16*)d_ws;
  _Float16* ARe = Bf + bf_elems;
  _Float16* AIm = ARe + af_elems;
  float* partial = (float*)(AIm + af_elems);

  const size_t base_bytes = (bf_elems + 2*af_elems) * sizeof(_Float16);
  const size_t per_xs     = (size_t)B_*C_*M_*2*sizeof(float);   // 524,288 B
  int XS = (ws_size >= base_bytes + 16*per_xs) ? 16 : 8;

  {
    int total = T1_ + T2_;          // 1,277,952 -> 4992 blocks exactly
    prep_fused<<<(total + 255)/256, 256, 0, stream>>>(xin, maps, coord, Bf, ARe, AIm);
  }
  if (XS == 16) {
    dim3 g(M_/128, 16, B_);         // 1024 blocks = 4/CU (VGPR/LDS permit it)
    main_mfma<5><<<g, 256, 0, stream>>>(coord, Bf, ARe, AIm, phi, partial);
  } else {
    dim3 g(M_/128, 8, B_);          // 512 blocks = 2/CU (r12-proven fallback)
    main_mfma<10><<<g, 256, 0, stream>>>(coord, Bf, ARe, AIm, phi, partial);
  }
  {
    int total = B_*C_*M_;           // 65,536
    combine3<<<(total + 255)/256, 256, 0, stream>>>(partial, out, XS);
  }
}

// Round 16
// 31.732 us; speedup vs baseline: 10.0605x; 1.3130x over previous
//
#include <hip/hip_runtime.h>
#include <hip/hip_fp16.h>
#include <math.h>

#define B_   2
#define C_   8
#define NB_  3
#define X_   80
#define Y_   80
#define M_   4096
#define P_   6400
#define NJ   24
#define KS   3          // k-steps of 32 (y padded 80->96)
#define NF   2          // n-frags (j padded 24->32)
#define XS_  8          // x-split across grid dim y
#define XPB_ (X_/XS_)   // 10 x-rows per block (5 pairs)
#define TWO_PI 6.2831853071795864769f

typedef _Float16 f16x8 __attribute__((ext_vector_type(8)));
typedef float    f32x4 __attribute__((ext_vector_type(4)));
typedef unsigned int u32x4 __attribute__((ext_vector_type(4)));

#define T1_ (B_*X_*KS*NF*64*8)   // 491,520
#define T2_ (B_*256*KS*512)      // 786,432

__device__ __forceinline__ int klocal(int lane, int i) {
  return ((lane >> 4) << 2) + (i & 3) + ((i >> 2) << 4);
}

__device__ __forceinline__ f16x8 negh8(f16x8 v) {
  u32x4 u = __builtin_bit_cast(u32x4, v);
  u ^= (u32x4){0x80008000u, 0x80008000u, 0x80008000u, 0x80008000u};
  return __builtin_bit_cast(f16x8, u);
}

// exact-reduced sincos of (-2*pi*t_rev): t in revolutions, |t| up to ~20.
// t - rintf(t) is exact in fp32; __sincosf then sees |arg| <= pi.
__device__ __forceinline__ void sincos_rev(float t, float* s, float* c) {
  t -= rintf(t);
  __sincosf(-TWO_PI * t, s, c);
}

// ---------- kernel 1 (fused prep): r10-verbatim (verified passing).
// Bf layout (f16): (b*80+x)*6144 + (ks*2+nf)*1024 + {0:re,512:im} + lane*8 + i
//   j-mapping: j = nb*8 + c
// A layout  (f16): ((b*256+m16)*3+ks)*512 + lane*8 + i   (includes 1/80 norm)
__global__ void prep_fused(const float* __restrict__ xin, const float* __restrict__ maps,
                           const float* __restrict__ coord,
                           _Float16* __restrict__ Bf,
                           _Float16* __restrict__ ARe, _Float16* __restrict__ AIm) {
  int t = blockIdx.x * blockDim.x + threadIdx.x;
  if (t < T1_) {
    int i    = t & 7;
    int lane = (t >> 3) & 63;
    int nf   = (t >> 9) & 1;
    int rest = t >> 10;
    int ks   = rest % 3; rest /= 3;
    int x    = rest % 80;
    int b    = rest / 80;

    int j = nf*16 + (lane & 15);
    int y = ks*32 + klocal(lane, i);
    float re = 0.f, im = 0.f;
    if (y < Y_ && j < NJ) {
      int c = j & 7, nb = j >> 3;
      int p = x*Y_ + y;
      const float* xp = xin  + (((size_t)b*NB_ + nb)*P_ + p)*2;
      const float* mp = maps + ((((size_t)b*C_ + c)*NB_ + nb)*P_ + p)*2;
      float xr = xp[0], xi2 = xp[1], mr = mp[0], mi = mp[1];
      re = mr*xr - mi*xi2;
      im = mr*xi2 + mi*xr;
    }
    size_t base = (size_t)((b*X_ + x)*6 + (ks*2 + nf)) * 1024;
    Bf[base + lane*8 + i]       = (_Float16)re;
    Bf[base + 512 + lane*8 + i] = (_Float16)im;
  } else {
    int u = t - T1_;
    int i    = u & 7;
    int lane = (u >> 3) & 63;
    int q    = u >> 9;           // (b*256 + m16)*3 + ks
    int ks   = q % 3;
    int bm   = q / 3;
    int m16  = bm & 255;
    int b    = bm >> 8;

    int m = m16*16 + (lane & 15);
    int y = ks*32 + klocal(lane, i);
    float re = 0.f, im = 0.f;
    if (y < Y_) {
      float c1 = coord[((size_t)b*M_ + m)*2 + 1];
      float s, c;
      sincos_rev(c1 * (float)(y - 40) * (1.0f/80.0f), &s, &c);
      re = c * (1.0f/80.0f);
      im = s * (1.0f/80.0f);
    }
    ARe[u] = (_Float16)re;
    AIm[u] = (_Float16)im;
  }
}

// Stage a PAIR of x-rows (24,576 B contiguous) global->LDS.
// 256 threads x 6 ops x 16 B/lane = 24,576 B. LDS dest wave-uniform base;
// bytes land LDS-linear == global-linear (r10-verified mechanism).
__device__ __forceinline__ void stage_b2(const _Float16* src, _Float16* dst, int tid) {
  int wave = tid >> 6, lane = tid & 63;
  #pragma unroll
  for (int u = 0; u < 6; u++) {
    int off = wave*6144 + u*1024;    // bytes
    __builtin_amdgcn_global_load_lds(
      (const __attribute__((address_space(1))) void*)((const char*)src + off + lane*16),
      (__attribute__((address_space(3))) void*)((char*)dst + off),
      16, 0, 0);
  }
}

// ---------- kernel 2: r10 main (bit-identical arithmetic) with ONE change:
// TWO x-rows per barrier interval (double-wide staged buffer, 5 barriers
// instead of 10). Each sub-iteration is the r10 body verbatim.
__global__ __launch_bounds__(256, 2) void main_mfma(
    const float* __restrict__ coord, const _Float16* __restrict__ Bf,
    const _Float16* __restrict__ ARe, const _Float16* __restrict__ AIm,
    const float* __restrict__ phi, float* __restrict__ partial) {
  __shared__ unsigned int extab[XPB_ * 128];   // packed half2(cos,sin), 5 KB
  __shared__ _Float16 bsm[2][12288];           // double-buffered x-row PAIR, 48 KB

  int mb   = blockIdx.x;          // 32 m-tiles of 128
  int xs   = blockIdx.y;          // x-split
  int b    = blockIdx.z;
  int tid  = threadIdx.x;
  int wave = tid >> 6, lane = tid & 63;
  int mblock = mb * 128;

  const _Float16* bfbase = Bf + (size_t)(b*X_ + xs*XPB_) * 6144;

  // prologue: stage pair 0 (rows 0,1) — drained by the first __syncthreads
  stage_b2(bfbase, bsm[0], tid);

  // ex table for THIS block's x-slice only: exp(-2*pi*i * coord0 * (x-40)/80)
  for (int t = tid; t < XPB_*128; t += 256) {
    int xloc = t >> 7, ml = t & 127;
    int x = xs*XPB_ + xloc;
    float c0 = coord[((size_t)b*M_ + mblock + ml)*2 + 0];
    float s, c;
    sincos_rev(c0 * (float)(x - 40) * (1.0f/80.0f), &s, &c);
    __half2 h = __floats2half2_rn(c, s);
    extab[t] = *(unsigned int*)&h;
  }

  // ey A-fragments: load precomputed (L2-resident)
  int mtile = mblock + wave*32;
  f16x8 ar[2][KS], ai[2][KS];
  #pragma unroll
  for (int mf = 0; mf < 2; mf++) {
    int m16 = (mtile >> 4) + mf;
    #pragma unroll
    for (int ks = 0; ks < KS; ks++) {
      size_t o = (((size_t)(b*256 + m16)*3 + ks)*512) + lane*8;
      ar[mf][ks] = *(const f16x8*)(ARe + o);
      ai[mf][ks] = *(const f16x8*)(AIm + o);
    }
  }
  __syncthreads();   // extab ready + stage(pair 0) drained (vmcnt 0 at barrier)

  f32x4 outr[2][NF], outi[2][NF];
  #pragma unroll
  for (int mf = 0; mf < 2; mf++)
    #pragma unroll
    for (int nf = 0; nf < NF; nf++) {
      outr[mf][nf] = (f32x4){0.f,0.f,0.f,0.f};
      outi[mf][nf] = (f32x4){0.f,0.f,0.f,0.f};
    }

  int cur = 0;
  for (int xp = 0; xp < XPB_/2; xp++) {
    // prefetch next pair; overlaps both sub-iterations below
    if (xp + 1 < XPB_/2)
      stage_b2(bfbase + (size_t)(xp + 1) * 12288, bsm[cur ^ 1], tid);

    for (int sub = 0; sub < 2; sub++) {
      int xi = xp*2 + sub;
      const _Float16* fb = bsm[cur] + sub*6144;
      f16x8 br[KS][NF], bi[KS][NF];
      #pragma unroll
      for (int ks = 0; ks < KS; ks++)
        #pragma unroll
        for (int nf = 0; nf < NF; nf++) {
          const _Float16* p = fb + (ks*2 + nf)*1024 + lane*8;
          br[ks][nf] = *(const f16x8*)p;
          bi[ks][nf] = *(const f16x8*)(p + 512);
        }

      f32x4 Tr[2][NF], Ti[2][NF];
      #pragma unroll
      for (int mf = 0; mf < 2; mf++)
        #pragma unroll
        for (int nf = 0; nf < NF; nf++) {
          Tr[mf][nf] = (f32x4){0.f,0.f,0.f,0.f};
          Ti[mf][nf] = (f32x4){0.f,0.f,0.f,0.f};
        }

      #pragma unroll
      for (int ks = 0; ks < KS; ks++)
        #pragma unroll
        for (int mf = 0; mf < 2; mf++)
          #pragma unroll
          for (int nf = 0; nf < NF; nf++) {
            Tr[mf][nf] = __builtin_amdgcn_mfma_f32_16x16x32_f16(ar[mf][ks],        br[ks][nf], Tr[mf][nf], 0, 0, 0);
            Tr[mf][nf] = __builtin_amdgcn_mfma_f32_16x16x32_f16(negh8(ai[mf][ks]), bi[ks][nf], Tr[mf][nf], 0, 0, 0);
            Ti[mf][nf] = __builtin_amdgcn_mfma_f32_16x16x32_f16(ar[mf][ks],        bi[ks][nf], Ti[mf][nf], 0, 0, 0);
            Ti[mf][nf] = __builtin_amdgcn_mfma_f32_16x16x32_f16(ai[mf][ks],        br[ks][nf], Ti[mf][nf], 0, 0, 0);
          }

      // epilogue: out += ex(m,x) * T   (extab reads are broadcast)
      #pragma unroll
      for (int mf = 0; mf < 2; mf++)
        #pragma unroll
        for (int r = 0; r < 4; r++) {
          int ml = wave*32 + mf*16 + ((lane >> 4) << 2) + r;
          unsigned int u = extab[xi*128 + ml];
          __half2 h = *(__half2*)&u;
          float exr = __low2float(h), exi = __high2float(h);
          #pragma unroll
          for (int nf = 0; nf < NF; nf++) {
            float tr = Tr[mf][nf][r], ti = Ti[mf][nf][r];
            outr[mf][nf][r] += exr*tr - exi*ti;
            outi[mf][nf][r] += exr*ti + exi*tr;
          }
        }
    }

    __syncthreads();   // all waves done with bsm[cur]; stage(next pair) drained
    cur ^= 1;
  }

  // ---- in-register phi + band reduction (r10 verbatim) ----
  int j0 = lane & 15;
  int row = (lane >> 4) << 2;
  const float* phb = phi + (size_t)b*NB_*M_*2;
  #pragma unroll
  for (int mf = 0; mf < 2; mf++)
    #pragma unroll
    for (int r = 0; r < 4; r++) {
      int m = mtile + mf*16 + row + r;
      const float* p0 = phb + ((size_t)(j0 >> 3)*M_ + m)*2;
      float p0r = p0[0], p0i = p0[1];
      float a0r = outr[mf][0][r], a0i = outi[mf][0][r];
      float vr = p0r*a0r - p0i*a0i;
      float vi = p0r*a0i + p0i*a0r;
      vr += __shfl_xor(vr, 8);
      vi += __shfl_xor(vi, 8);
      const float* p1 = phb + ((size_t)2*M_ + m)*2;
      float p1r = p1[0], p1i = p1[1];
      float a1r = outr[mf][1][r], a1i = outi[mf][1][r];
      vr += p1r*a1r - p1i*a1i;
      vi += p1r*a1i + p1i*a1r;
      if (j0 < 8) {
        int c = j0;
        size_t o = (((size_t)xs*B_ + b)*C_ + c)*M_ + m;
        ((float2*)partial)[o] = make_float2(vr, vi);
      }
    }
}

// ---------- kernel 3: r10 combine3, verbatim
__global__ void combine3(const float* __restrict__ partial, float* __restrict__ out) {
  int t = blockIdx.x * blockDim.x + threadIdx.x;   // (b, c, m), m fastest
  if (t >= B_*C_*M_) return;
  int m = t & (M_ - 1);
  int c = (t >> 12) & 7;
  int b = t >> 15;
  float sr = 0.f, si = 0.f;
  #pragma unroll
  for (int xs = 0; xs < XS_; xs++) {
    const float2 v = ((const float2*)partial)[(((size_t)xs*B_ + b)*C_ + c)*M_ + m];
    sr += v.x; si += v.y;
  }
  ((float2*)out)[((size_t)b*C_ + c)*M_ + m] = make_float2(sr, si);
}

extern "C" void kernel_launch(void* const* d_in, const int* in_sizes, int n_in,
                              void* d_out, int out_size, void* d_ws, size_t ws_size,
                              hipStream_t stream) {
  const float* xin   = (const float*)d_in[0];
  const float* maps  = (const float*)d_in[1];
  const float* phi   = (const float*)d_in[2];
  const float* coord = (const float*)d_in[3];
  float* out = (float*)d_out;

  const size_t bf_elems = (size_t)B_ * X_ * 6144;        // 983,040 f16
  const size_t af_elems = (size_t)B_ * 256 * KS * 512;   // 786,432 f16
  _Float16* Bf  = (_Float16*)d_ws;
  _Float16* ARe = Bf + bf_elems;
  _Float16* AIm = ARe + af_elems;
  float* partial = (float*)(AIm + af_elems);             // XS_*B*C*M*2 floats

  {
    int total = T1_ + T2_;          // 1,277,952 -> 4992 blocks exactly
    prep_fused<<<(total + 255)/256, 256, 0, stream>>>(xin, maps, coord, Bf, ARe, AIm);
  }
  {
    dim3 g(M_/128, XS_, B_);        // 512 blocks
    main_mfma<<<g, 256, 0, stream>>>(coord, Bf, ARe, AIm, phi, partial);
  }
  {
    int total = B_*C_*M_;           // 65,536
    combine3<<<(total + 255)/256, 256, 0, stream>>>(partial, out);
  }
}